// Round 1
// 142.499 us; speedup vs baseline: 1.0836x; 1.0836x over previous
//
#include <hip/hip_runtime.h>

#define BB 8
#define SS 2048
#define DD 128
#define ROWS 16            // q rows per block
#define NW 8               // waves per block (512 threads)
#define CTW 16             // col-tiles (of 16) per wave -> 256 cols/wave

typedef short bf16x8 __attribute__((ext_vector_type(8)));
typedef float f32x4 __attribute__((ext_vector_type(4)));

template <int I> struct IC { static constexpr int value = I; };
template <int I, int N, typename F>
__device__ __forceinline__ void sfor(F&& f) {
  if constexpr (I < N) { f(IC<I>{}); sfor<I + 1, N>((F&&)f); }
}

__device__ __forceinline__ short f2bf(float x) {
  return __builtin_bit_cast(short, (__bf16)x);
}
__device__ __forceinline__ float bf2f(short u) {
  return __uint_as_float(((unsigned)(unsigned short)u) << 16);
}

// ---- prep: Khi = bf16(K) in MFMA B-fragment order ----
// Frag (b,ct,s,lane): lane(quad,m16) holds K[b][ct*16+m16][s*32+quad*8 .. +8]
__global__ __launch_bounds__(256)
void ksplit(const float* __restrict__ K, short* __restrict__ Khi) {
  const int lin  = blockIdx.x * 256 + threadIdx.x;   // 262144 frags
  const int b    = lin >> 15;
  const int rem  = lin & 32767;
  const int ct   = rem >> 8;
  const int s    = (rem >> 6) & 3;
  const int lane = rem & 63;
  const int quad = lane >> 4, m16 = lane & 15;
  const size_t elem = (size_t)(b * SS + ct * 16 + m16) * DD + s * 32 + quad * 8;
  const float4 v0 = *(const float4*)(K + elem);
  const float4 v1 = *(const float4*)(K + elem + 4);
  const float f[8] = {v0.x, v0.y, v0.z, v0.w, v1.x, v1.y, v1.z, v1.w};
  bf16x8 h;
#pragma unroll
  for (int e = 0; e < 8; ++e) h[e] = f2bf(f[e]);
  *(bf16x8*)(Khi + (size_t)lin * 8) = h;      // fragment order
}

// ---- fused entmax attention: single-term bf16 screen + exact fp32 candidate refine ----
// waves_per_eu(4): cap total regs at 128/wave (64 acc AGPR + ~60 arch) -> 2 blocks/CU
__global__ __launch_bounds__(512) __attribute__((amdgpu_waves_per_eu(4)))
void attn(const float* __restrict__ Q, const short* __restrict__ Khi,
          const float* __restrict__ K, const float* __restrict__ V,
          float* __restrict__ Out) {
  __shared__ unsigned short Qs[ROWS][136];     // bf16(0.5*Q), A-operand layout
  __shared__ float rbuf[ROWS][64];             // candidate VALUES (then exact)
  __shared__ int   scol[ROWS][64];             // candidate COLUMNS
  __shared__ float exM[NW][ROWS];
  __shared__ float exZ[NW][ROWS];              // slow bisection only
  __shared__ int   rcnt[ROWS];
  __shared__ float tauB[ROWS], ZB[ROWS];
  __shared__ int   flagv;
  __shared__ float obuf[ROWS][DD];             // dense fallback only

  const int tid  = threadIdx.x;
  const int lane = tid & 63;
  const int wid  = __builtin_amdgcn_readfirstlane(tid >> 6);  // 0..7
  const int quad = lane >> 4, m16 = lane & 15;
  const int b    = blockIdx.x & 7;             // batch -> XCD pinning
  const int qt   = blockIdx.x >> 3;            // 0..127

  const float* Qb = Q + (size_t)(b * SS + qt * ROWS) * DD;
  const float* Kb = K + (size_t)b * SS * DD;
  const float* Vb = V + (size_t)b * SS * DD;
  float*       Ob = Out + (size_t)(b * SS + qt * ROWS) * DD;
  const short* KHb = Khi + (size_t)b * SS * DD;

  if (tid < ROWS) rcnt[tid] = 0;
  if (tid == ROWS) flagv = 0;

  // ---- stage Q once: bf16(0.5*q), A-operand layout ----
  {
    const int row = tid >> 5, d = (tid & 31) * 4;
    const float4 v = *(const float4*)&Qb[row * DD + d];
    ushort4 h;
    h.x = (unsigned short)f2bf(0.5f * v.x);
    h.y = (unsigned short)f2bf(0.5f * v.y);
    h.z = (unsigned short)f2bf(0.5f * v.z);
    h.w = (unsigned short)f2bf(0.5f * v.w);
    *(ushort4*)&Qs[row][d] = h;
  }
  __syncthreads();

  bf16x8 qh[4];
#pragma unroll
  for (int s = 0; s < 4; ++s)
    qh[s] = *(const bf16x8*)&Qs[m16][s * 32 + quad * 8];

  // ---- phase 1: z_a = bf16(0.5Q) * Khi^T, single term, B-frags from global ----
  f32x4 acc[CTW];
  sfor<0, CTW>([&](auto ic) {
    constexpr int i = ic.value;
    const int ct = wid * CTW + i;
    const short* bh0 = KHb + ((size_t)ct << 11) + lane * 8;
    f32x4 c = {0.f, 0.f, 0.f, 0.f};
    sfor<0, 4>([&](auto sc) {
      constexpr int s = sc.value;
      const bf16x8 bh = *(const bf16x8*)(bh0 + (s << 9));
      c = __builtin_amdgcn_mfma_f32_16x16x32_bf16(qh[s], bh, c, 0, 0, 0);
    });
    acc[i] = c;
  });
  // lane holds z_a[row=4*quad+j][col = wid*256 + i*16 + m16]; |z_a - z| std ~0.009

  // ---- row max of z_a ----
  float mx[4] = {-1e38f, -1e38f, -1e38f, -1e38f};
  sfor<0, CTW>([&](auto ic) {
#pragma unroll
    for (int j = 0; j < 4; ++j) mx[j] = fmaxf(mx[j], acc[ic.value][j]);
  });
#pragma unroll
  for (int j = 0; j < 4; ++j)
#pragma unroll
    for (int s = 1; s <= 8; s <<= 1) mx[j] = fmaxf(mx[j], __shfl_xor(mx[j], s));
  if (m16 == 0) {
#pragma unroll
    for (int j = 0; j < 4; ++j) exM[wid][4 * quad + j] = mx[j];
  }
  __syncthreads();
  float M4[4];
#pragma unroll
  for (int j = 0; j < 4; ++j) {
    float m = -1e38f;
#pragma unroll
    for (int w = 0; w < NW; ++w) m = fmaxf(m, exM[w][4 * quad + j]);
    M4[j] = m;
  }

  // ---- compact candidates: z_a > M_a - 1.25 (margin = 1 + ~13 sigma of z_a err) ----
  sfor<0, CTW>([&](auto ic) {
    constexpr int i = ic.value;
    const int col = wid * 256 + i * 16 + m16;
#pragma unroll
    for (int j = 0; j < 4; ++j) {
      const int row = 4 * quad + j;
      if (acc[i][j] > M4[j] - 1.25f) {
        const int pos = atomicAdd(&rcnt[row], 1);
        if (pos < 64) { scol[row][pos] = col; rbuf[row][pos] = acc[i][j]; }
        else atomicOr(&flagv, 1);
      }
    }
  });
  __syncthreads();

  // ---- refine candidates EXACTLY: z = 0.5 * dot_f32(Q[row], K[c]) ----
  if (flagv == 0) {
#pragma unroll
    for (int rr = 0; rr < 2; ++rr) {
      const int row = 2 * wid + rr;
      const int n = rcnt[row];
      const float2 q2 = *(const float2*)&Qb[row * DD + lane * 2];
      for (int i = 0; i < n; ++i) {
        const int c = scol[row][i];
        const float2 k2 = *(const float2*)&Kb[(size_t)c * DD + lane * 2];
        float t = fmaf(q2.x, k2.x, q2.y * k2.y);
#pragma unroll
        for (int s = 1; s <= 32; s <<= 1) t += __shfl_xor(t, s);
        if (lane == 0) rbuf[row][i] = 0.5f * t;
      }
    }
  }
  __syncthreads();

  // ---- bisection ----
  float tau4[4], Z4[4];   // slow path state
  if (flagv == 0) {
    // fast: all waves redundantly bisect all 16 rows; candidates cached in regs
    const int row = lane >> 2;
    const int n = rcnt[row];
    float cv[16];
#pragma unroll
    for (int k = 0; k < 16; ++k) {
      const int i = (lane & 3) + 4 * k;
      cv[k] = (i < n) ? rbuf[row][i] : -1e38f;
    }
    float Mr = cv[0];
#pragma unroll
    for (int k = 1; k < 16; ++k) Mr = fmaxf(Mr, cv[k]);
    Mr = fmaxf(Mr, __shfl_xor(Mr, 1));
    Mr = fmaxf(Mr, __shfl_xor(Mr, 2));
    float tmn = Mr - 1.0f, tmx = Mr - 0.022097086912079608f;  // S^(1-alpha)
    float tau = 0.5f * (tmn + tmx), Zr = 0.f;
    for (int it = 0; it < 100; ++it) {
      tau = 0.5f * (tmn + tmx);
      float z0 = 0.f, z1 = 0.f, z2 = 0.f, z3 = 0.f;
#pragma unroll
      for (int k = 0; k < 16; k += 4) {
        const float t0 = fmaxf(cv[k + 0] - tau, 0.f); z0 = fmaf(t0, t0, z0);
        const float t1 = fmaxf(cv[k + 1] - tau, 0.f); z1 = fmaf(t1, t1, z1);
        const float t2 = fmaxf(cv[k + 2] - tau, 0.f); z2 = fmaf(t2, t2, z2);
        const float t3 = fmaxf(cv[k + 3] - tau, 0.f); z3 = fmaf(t3, t3, z3);
      }
      float zp = (z0 + z1) + (z2 + z3);
      zp += __shfl_xor(zp, 1);
      zp += __shfl_xor(zp, 2);
      Zr = zp;
      const float nmn = (zp >= 1.f) ? tau : tmn;
      const float nmx = (zp >= 1.f) ? tmx : tau;
      const bool ch = (nmn != tmn) || (nmx != tmx);
      tmn = nmn; tmx = nmx;
      if (!__any(ch)) break;   // fixed point: faithful to 100 iters
    }
    if (wid == 0 && (lane & 3) == 0) { tauB[row] = tau; ZB[row] = Zr; }
  } else {
    // slow: dense bisection on z_a (unreachable on sane data)
    float tmn4[4], tmx4[4];
#pragma unroll
    for (int j = 0; j < 4; ++j) {
      tmn4[j] = M4[j] - 1.0f; tmx4[j] = M4[j] - 0.022097086912079608f;
      tau4[j] = 0.5f * (tmn4[j] + tmx4[j]); Z4[j] = 0.f;
    }
    for (int it = 0; it < 100; ++it) {
      float zp[4] = {0.f, 0.f, 0.f, 0.f};
#pragma unroll
      for (int j = 0; j < 4; ++j) tau4[j] = 0.5f * (tmn4[j] + tmx4[j]);
      sfor<0, CTW>([&](auto ic) {
#pragma unroll
        for (int j = 0; j < 4; ++j) {
          const float tt = fmaxf(acc[ic.value][j] - tau4[j], 0.f);
          zp[j] = fmaf(tt, tt, zp[j]);
        }
      });
#pragma unroll
      for (int j = 0; j < 4; ++j)
#pragma unroll
        for (int s = 1; s <= 8; s <<= 1) zp[j] += __shfl_xor(zp[j], s);
      if (m16 == 0) {
#pragma unroll
        for (int j = 0; j < 4; ++j) exZ[wid][4 * quad + j] = zp[j];
      }
      __syncthreads();
      bool ch = false;
#pragma unroll
      for (int j = 0; j < 4; ++j) {
        float Zf = 0.f;
#pragma unroll
        for (int w = 0; w < NW; ++w) Zf += exZ[w][4 * quad + j];
        Z4[j] = Zf;
        const float nmn = (Zf >= 1.f) ? tau4[j] : tmn4[j];
        const float nmx = (Zf >= 1.f) ? tmx4[j] : tau4[j];
        ch = ch || (nmn != tmn4[j]) || (nmx != tmx4[j]);
        tmn4[j] = nmn; tmx4[j] = nmx;
      }
      __syncthreads();
      if (!ch) break;          // Zf block-uniform -> barrier-safe
    }
  }
  __syncthreads();

  if (flagv == 0) {
    // ---- O = sum p_i * V[col_i], fp32, coalesced; p recomputed from LDS broadcast ----
#pragma unroll
    for (int rr = 0; rr < 2; ++rr) {
      const int row = 2 * wid + rr;
      const int n = rcnt[row];
      const float tau = tauB[row];
      const float iz  = 1.0f / ZB[row];
      float2 o = {0.f, 0.f};
      for (int i = 0; i < n; ++i) {
        const float rv = rbuf[row][i];          // same addr all lanes -> broadcast
        const float tt = fmaxf(rv - tau, 0.f);
        const float pi = tt * tt * iz;
        const int   c  = scol[row][i];
        const float2 v2 = *(const float2*)&Vb[(size_t)c * DD + lane * 2];
        o.x = fmaf(pi, v2.x, o.x);
        o.y = fmaf(pi, v2.y, o.y);
      }
      *(float2*)&Ob[row * DD + lane * 2] = o;
    }
  } else {
    // ---- dense fallback output from z_a ----
    for (int i = tid; i < ROWS * DD; i += 512) ((float*)obuf)[i] = 0.f;
    __syncthreads();
    sfor<0, CTW>([&](auto ic) {
      constexpr int i = ic.value;
      const int col = wid * 256 + i * 16 + m16;
#pragma unroll
      for (int j = 0; j < 4; ++j) {
        const int row = 4 * quad + j;
        const float tt = fmaxf(acc[i][j] - tau4[j], 0.f);
        const float p = tt * tt / Z4[j];
        if (p > 0.f) {
          for (int d = 0; d < DD; ++d)
            atomicAdd(&obuf[row][d], p * Vb[(size_t)col * DD + d]);
        }
      }
    });
    __syncthreads();
    for (int i = tid; i < ROWS * DD; i += 512) {
      const int row = i >> 7, d = i & 127;
      Ob[row * DD + d] = obuf[row][d];
    }
  }
}

extern "C" void kernel_launch(void* const* d_in, const int* in_sizes, int n_in,
                              void* d_out, int out_size, void* d_ws, size_t ws_size,
                              hipStream_t stream) {
  const float* Q = (const float*)d_in[0];
  const float* K = (const float*)d_in[1];
  const float* V = (const float*)d_in[2];
  float* out = (float*)d_out;
  short* Khi = (short*)d_ws;                      // 4 MiB, fragment order

  hipLaunchKernelGGL(ksplit, dim3(BB * SS * DD / (256 * 8)), dim3(256), 0, stream,
                     K, Khi);
  hipLaunchKernelGGL(attn, dim3(BB * (SS / ROWS)), dim3(512), 0, stream,
                     Q, Khi, K, V, out);
}

// Round 2
// 137.426 us; speedup vs baseline: 1.1236x; 1.0369x over previous
//
#include <hip/hip_runtime.h>

#define BB 8
#define SS 2048
#define DD 128
#define ROWS 16            // q rows per block
#define NW 8               // waves per block (512 threads)
#define CTW 16             // col-tiles (of 16) per wave -> 256 cols/wave

typedef short bf16x8 __attribute__((ext_vector_type(8)));
typedef float f32x4 __attribute__((ext_vector_type(4)));

template <int I> struct IC { static constexpr int value = I; };
template <int I, int N, typename F>
__device__ __forceinline__ void sfor(F&& f) {
  if constexpr (I < N) { f(IC<I>{}); sfor<I + 1, N>((F&&)f); }
}

__device__ __forceinline__ short f2bf(float x) {
  return __builtin_bit_cast(short, (__bf16)x);
}
__device__ __forceinline__ float bf2f(short u) {
  return __uint_as_float(((unsigned)(unsigned short)u) << 16);
}

// async DMA one 1KB segment: 64 lanes x 16B, LDS dest = uniform base + lane*16
__device__ __forceinline__ void stage_tile(const short* g, short* l) {
#pragma unroll
  for (int s = 0; s < 4; ++s) {
    __builtin_amdgcn_global_load_lds(
        (const __attribute__((address_space(1))) void*)(g + (s << 9)),
        (__attribute__((address_space(3))) void*)(l + (s << 9)), 16, 0, 0);
  }
}

// ---- prep: Khi = bf16(K) in MFMA B-fragment order ----
// Frag (b,ct,s,lane): lane(quad,m16) holds K[b][ct*16+m16][s*32+quad*8 .. +8]
__global__ __launch_bounds__(256)
void ksplit(const float* __restrict__ K, short* __restrict__ Khi) {
  const int lin  = blockIdx.x * 256 + threadIdx.x;   // 262144 frags
  const int b    = lin >> 15;
  const int rem  = lin & 32767;
  const int ct   = rem >> 8;
  const int s    = (rem >> 6) & 3;
  const int lane = rem & 63;
  const int quad = lane >> 4, m16 = lane & 15;
  const size_t elem = (size_t)(b * SS + ct * 16 + m16) * DD + s * 32 + quad * 8;
  const float4 v0 = *(const float4*)(K + elem);
  const float4 v1 = *(const float4*)(K + elem + 4);
  const float f[8] = {v0.x, v0.y, v0.z, v0.w, v1.x, v1.y, v1.z, v1.w};
  bf16x8 h;
#pragma unroll
  for (int e = 0; e < 8; ++e) h[e] = f2bf(f[e]);
  *(bf16x8*)(Khi + (size_t)lin * 8) = h;      // fragment order
}

// ---- fused entmax attention: async-LDS-ring bf16 screen + exact fp32 candidate refine ----
__global__ __launch_bounds__(512) __attribute__((amdgpu_waves_per_eu(4)))
void attn(const float* __restrict__ Q, const short* __restrict__ Khi,
          const float* __restrict__ K, const float* __restrict__ V,
          float* __restrict__ Out) {
  __shared__ short kring[NW][2][2048];         // per-wave 2-slot tile ring (64 KiB)
  __shared__ unsigned short Qs[ROWS][136];     // bf16(0.5*Q), A-operand layout
  __shared__ float rbuf[ROWS][64];             // candidate VALUES (then exact)
  __shared__ int   scol[ROWS][64];             // candidate COLUMNS
  __shared__ float exM[NW][ROWS];
  __shared__ float exZ[NW][ROWS];              // slow bisection only
  __shared__ int   rcnt[ROWS];
  __shared__ float tauB[ROWS], ZB[ROWS];
  __shared__ int   flagv;

  const int tid  = threadIdx.x;
  const int lane = tid & 63;
  const int wid  = __builtin_amdgcn_readfirstlane(tid >> 6);  // 0..7
  const int quad = lane >> 4, m16 = lane & 15;
  const int b    = blockIdx.x & 7;             // batch -> XCD pinning
  const int qt   = blockIdx.x >> 3;            // 0..127

  const float* Qb = Q + (size_t)(b * SS + qt * ROWS) * DD;
  const float* Kb = K + (size_t)b * SS * DD;
  const float* Vb = V + (size_t)b * SS * DD;
  float*       Ob = Out + (size_t)(b * SS + qt * ROWS) * DD;
  const short* KHb = Khi + (size_t)b * SS * DD;

  if (tid < ROWS) rcnt[tid] = 0;
  if (tid == ROWS) flagv = 0;

  // ---- stage Q once: bf16(0.5*q), A-operand layout ----
  {
    const int row = tid >> 5, d = (tid & 31) * 4;
    const float4 v = *(const float4*)&Qb[row * DD + d];
    ushort4 h;
    h.x = (unsigned short)f2bf(0.5f * v.x);
    h.y = (unsigned short)f2bf(0.5f * v.y);
    h.z = (unsigned short)f2bf(0.5f * v.z);
    h.w = (unsigned short)f2bf(0.5f * v.w);
    *(ushort4*)&Qs[row][d] = h;
  }
  __syncthreads();   // also drains vmcnt -> ring counting below starts clean

  bf16x8 qh[4];
#pragma unroll
  for (int s = 0; s < 4; ++s)
    qh[s] = *(const bf16x8*)&Qs[m16][s * 32 + quad * 8];

  // ---- phase 1: z_a = bf16(0.5Q) * Khi^T via per-wave async LDS ring ----
  // wave 'wid' owns tiles ct = wid*16 + i; each tile consumed only by its
  // loader wave -> barrier-free double-buffered pipeline, vmcnt-counted.
  short* ring0 = &kring[wid][0][0];
  short* ring1 = &kring[wid][1][0];
  const short* gw = KHb + ((size_t)(wid * CTW) << 11) + lane * 8;

  stage_tile(gw + 0 * 2048, ring0);
  stage_tile(gw + 1 * 2048, ring1);

  f32x4 acc[CTW];
  sfor<0, CTW>([&](auto ic) {
    constexpr int i = ic.value;
    if constexpr (i < CTW - 1) asm volatile("s_waitcnt vmcnt(4)" ::: "memory");
    else                       asm volatile("s_waitcnt vmcnt(0)" ::: "memory");
    const short* sbl = ((i & 1) ? ring1 : ring0) + lane * 8;
    f32x4 c = {0.f, 0.f, 0.f, 0.f};
    sfor<0, 4>([&](auto sc) {
      constexpr int s = sc.value;
      const bf16x8 bh = *(const bf16x8*)(sbl + (s << 9));
      c = __builtin_amdgcn_mfma_f32_16x16x32_bf16(qh[s], bh, c, 0, 0, 0);
    });
    acc[i] = c;
    if constexpr (i + 2 < CTW) {
      asm volatile("s_waitcnt lgkmcnt(0)" ::: "memory");  // reads retired before overwrite
      stage_tile(gw + (i + 2) * 2048, (i & 1) ? ring1 : ring0);
    }
  });
  // lane holds z_a[row=4*quad+j][col = wid*256 + i*16 + m16]; |z_a - z| std ~0.009

  // ---- row max of z_a ----
  float mx[4] = {-1e38f, -1e38f, -1e38f, -1e38f};
  sfor<0, CTW>([&](auto ic) {
#pragma unroll
    for (int j = 0; j < 4; ++j) mx[j] = fmaxf(mx[j], acc[ic.value][j]);
  });
#pragma unroll
  for (int j = 0; j < 4; ++j)
#pragma unroll
    for (int s = 1; s <= 8; s <<= 1) mx[j] = fmaxf(mx[j], __shfl_xor(mx[j], s));
  if (m16 == 0) {
#pragma unroll
    for (int j = 0; j < 4; ++j) exM[wid][4 * quad + j] = mx[j];
  }
  __syncthreads();
  float M4[4];
#pragma unroll
  for (int j = 0; j < 4; ++j) {
    float m = -1e38f;
#pragma unroll
    for (int w = 0; w < NW; ++w) m = fmaxf(m, exM[w][4 * quad + j]);
    M4[j] = m;
  }

  // ---- compact candidates: z_a > M_a - 1.25 (margin = 1 + ~13 sigma of z_a err) ----
  sfor<0, CTW>([&](auto ic) {
    constexpr int i = ic.value;
    const int col = wid * 256 + i * 16 + m16;
#pragma unroll
    for (int j = 0; j < 4; ++j) {
      const int row = 4 * quad + j;
      if (acc[i][j] > M4[j] - 1.25f) {
        const int pos = atomicAdd(&rcnt[row], 1);
        if (pos < 64) { scol[row][pos] = col; rbuf[row][pos] = acc[i][j]; }
        else atomicOr(&flagv, 1);
      }
    }
  });
  __syncthreads();

  if (flagv == 0) {
    // ======== fast path: everything below is wave-local (rows 2*wid, 2*wid+1) ========

    // ---- refine candidates EXACTLY: z = 0.5 * dot_f32(Q[row], K[c]) ----
#pragma unroll
    for (int rr = 0; rr < 2; ++rr) {
      const int row = 2 * wid + rr;
      const int n = rcnt[row];
      const float2 q2 = *(const float2*)&Qb[row * DD + lane * 2];
      for (int i = 0; i < n; ++i) {
        const int c = scol[row][i];
        const float2 k2 = *(const float2*)&Kb[(size_t)c * DD + lane * 2];
        float t = fmaf(q2.x, k2.x, q2.y * k2.y);
#pragma unroll
        for (int s = 1; s <= 32; s <<= 1) t += __shfl_xor(t, s);
        if (lane == 0) rbuf[row][i] = 0.5f * t;
      }
    }

    // ---- bisection: 32 lanes per row, candidates in 2 registers ----
    {
      const int rr32 = lane >> 5;                 // 0/1 -> which of this wave's rows
      const int row  = 2 * wid + rr32;
      const int l32  = lane & 31;
      const int n = rcnt[row];
      const float a0 = (l32 < n)      ? rbuf[row][l32]      : -1e38f;
      const float a1 = (l32 + 32 < n) ? rbuf[row][l32 + 32] : -1e38f;
      float Mr = fmaxf(a0, a1);
#pragma unroll
      for (int s = 1; s <= 16; s <<= 1) Mr = fmaxf(Mr, __shfl_xor(Mr, s));
      float tmn = Mr - 1.0f, tmx = Mr - 0.022097086912079608f;  // S^(1-alpha)
      float tau = 0.5f * (tmn + tmx), Zr = 0.f;
      for (int it = 0; it < 100; ++it) {
        tau = 0.5f * (tmn + tmx);
        const float t0 = fmaxf(a0 - tau, 0.f);
        const float t1 = fmaxf(a1 - tau, 0.f);
        float zp = fmaf(t0, t0, t1 * t1);
#pragma unroll
        for (int s = 1; s <= 16; s <<= 1) zp += __shfl_xor(zp, s);
        Zr = zp;
        const float nmn = (zp >= 1.f) ? tau : tmn;
        const float nmx = (zp >= 1.f) ? tmx : tau;
        const bool ch = (nmn != tmn) || (nmx != tmx);
        tmn = nmn; tmx = nmx;
        if (!__any(ch)) break;   // fixed point: faithful to 100 iters
      }
      if (l32 == 0) { tauB[row] = tau; ZB[row] = Zr; }
    }
    // tauB/ZB/rbuf written+read by this same wave only -> no barrier

    // ---- O = sum p_i * V[col_i], fp32, coalesced; p recomputed from LDS broadcast ----
#pragma unroll
    for (int rr = 0; rr < 2; ++rr) {
      const int row = 2 * wid + rr;
      const int n = rcnt[row];
      const float tau = tauB[row];
      const float iz  = 1.0f / ZB[row];
      float2 o = {0.f, 0.f};
      for (int i = 0; i < n; ++i) {
        const float rv = rbuf[row][i];          // same addr all lanes -> broadcast
        const float tt = fmaxf(rv - tau, 0.f);
        const float pi = tt * tt * iz;
        const int   c  = scol[row][i];
        const float2 v2 = *(const float2*)&Vb[(size_t)c * DD + lane * 2];
        o.x = fmaf(pi, v2.x, o.x);
        o.y = fmaf(pi, v2.y, o.y);
      }
      *(float2*)&Ob[row * DD + lane * 2] = o;
    }
  } else {
    // ======== slow path (unreachable on sane data): dense bisection on z_a ========
    float tau4[4], Z4[4];
    float tmn4[4], tmx4[4];
#pragma unroll
    for (int j = 0; j < 4; ++j) {
      tmn4[j] = M4[j] - 1.0f; tmx4[j] = M4[j] - 0.022097086912079608f;
      tau4[j] = 0.5f * (tmn4[j] + tmx4[j]); Z4[j] = 0.f;
    }
    for (int it = 0; it < 100; ++it) {
      float zp[4] = {0.f, 0.f, 0.f, 0.f};
#pragma unroll
      for (int j = 0; j < 4; ++j) tau4[j] = 0.5f * (tmn4[j] + tmx4[j]);
      sfor<0, CTW>([&](auto ic) {
#pragma unroll
        for (int j = 0; j < 4; ++j) {
          const float tt = fmaxf(acc[ic.value][j] - tau4[j], 0.f);
          zp[j] = fmaf(tt, tt, zp[j]);
        }
      });
#pragma unroll
      for (int j = 0; j < 4; ++j)
#pragma unroll
        for (int s = 1; s <= 8; s <<= 1) zp[j] += __shfl_xor(zp[j], s);
      if (m16 == 0) {
#pragma unroll
        for (int j = 0; j < 4; ++j) exZ[wid][4 * quad + j] = zp[j];
      }
      __syncthreads();
      bool ch = false;
#pragma unroll
      for (int j = 0; j < 4; ++j) {
        float Zf = 0.f;
#pragma unroll
        for (int w = 0; w < NW; ++w) Zf += exZ[w][4 * quad + j];
        Z4[j] = Zf;
        const float nmn = (Zf >= 1.f) ? tau4[j] : tmn4[j];
        const float nmx = (Zf >= 1.f) ? tmx4[j] : tau4[j];
        ch = ch || (nmn != tmn4[j]) || (nmx != tmx4[j]);
        tmn4[j] = nmn; tmx4[j] = nmx;
      }
      __syncthreads();
      if (!ch) break;          // Zf block-uniform -> barrier-safe
    }

    // ---- dense fallback output; obuf aliased onto dead kring ----
    float (*obuf)[DD] = (float (*)[DD])&kring[0][0][0];
    for (int i = tid; i < ROWS * DD; i += 512) ((float*)obuf)[i] = 0.f;
    __syncthreads();
    sfor<0, CTW>([&](auto ic) {
      constexpr int i = ic.value;
      const int col = wid * 256 + i * 16 + m16;
#pragma unroll
      for (int j = 0; j < 4; ++j) {
        const int row = 4 * quad + j;
        const float tt = fmaxf(acc[i][j] - tau4[j], 0.f);
        const float p = tt * tt / Z4[j];
        if (p > 0.f) {
          for (int d = 0; d < DD; ++d)
            atomicAdd(&obuf[row][d], p * Vb[(size_t)col * DD + d]);
        }
      }
    });
    __syncthreads();
    for (int i = tid; i < ROWS * DD; i += 512) {
      const int row = i >> 7, d = i & 127;
      Ob[row * DD + d] = obuf[row][d];
    }
  }
}

extern "C" void kernel_launch(void* const* d_in, const int* in_sizes, int n_in,
                              void* d_out, int out_size, void* d_ws, size_t ws_size,
                              hipStream_t stream) {
  const float* Q = (const float*)d_in[0];
  const float* K = (const float*)d_in[1];
  const float* V = (const float*)d_in[2];
  float* out = (float*)d_out;
  short* Khi = (short*)d_ws;                      // 4 MiB, fragment order

  hipLaunchKernelGGL(ksplit, dim3(BB * SS * DD / (256 * 8)), dim3(256), 0, stream,
                     K, Khi);
  hipLaunchKernelGGL(attn, dim3(BB * (SS / ROWS)), dim3(512), 0, stream,
                     Q, Khi, K, V, out);
}